// Round 2
// baseline (1026.567 us; speedup 1.0000x reference)
//
#include <hip/hip_runtime.h>
#include <hip/hip_bf16.h>
#include <math.h>

// RWKV-7 Tmix forward, B=4 T=1024 C=1024 H=16 N=64.
// Input dtype (f32 vs bf16) detected at runtime from bit patterns; all
// compute in bf16 MFMA + f32 accum. PKb [BT][H][5][64] bf16 (r,k,v,a,b),
// PKw [BT][C] f32 (decay). ws ~116 MiB.

using bf16 = __hip_bfloat16;
typedef __attribute__((ext_vector_type(8))) short bf16x8;
typedef __attribute__((ext_vector_type(4))) float f32x4;

#define DEVINL __device__ __forceinline__

DEVINL float b2f(bf16 v) { return __bfloat162float(v); }
DEVINL bf16 f2b(float f) { return __float2bfloat16(f); }
DEVINL float sigm(float x) { return 1.f / (1.f + __expf(-x)); }
DEVINL float bfbits2f(unsigned short s) { return __uint_as_float(((unsigned)s) << 16); }
DEVINL float ldin(const void* p, size_t i, int fl) {
  return fl ? ((const float*)p)[i] : b2f(((const bf16*)p)[i]);
}

DEVINL void g2lds16(const void* g, void* l) {
  __builtin_amdgcn_global_load_lds(
      (__attribute__((address_space(1))) void*)(g),
      (__attribute__((address_space(3))) void*)(l), 16, 0, 0);
}

// ---------------- dtype probe: flag=1 -> inputs are f32 ----------------
__global__ void detect_kernel(const unsigned* __restrict__ x, int* __restrict__ flag) {
  __shared__ int cnt[4];
  int tid = threadIdx.x;
  unsigned w = x[tid];
  float v = fabsf(bfbits2f((unsigned short)(w & 0xffffu)));
  bool plaus = (v >= 1e-4f && v <= 16.f);           // low half looks like bf16 N(0,1)?
  unsigned long long m = __ballot(plaus);
  if ((tid & 63) == 0) cnt[tid >> 6] = __popcll(m);
  __syncthreads();
  if (tid == 0) *flag = (cnt[0] + cnt[1] + cnt[2] + cnt[3] < 128) ? 1 : 0;
}

// ---------------- big-weight convert (4 x 1M elements) ----------------
__global__ __launch_bounds__(256)
void cvtw_kernel(const void* s0, const void* s1, const void* s2, const void* s3,
                 bf16* d0, bf16* d1, bf16* d2, bf16* d3, const int* __restrict__ flag) {
  int fl = *flag;
  int g = blockIdx.x * 256 + threadIdx.x;            // 0 .. 4M
  int seg = g >> 20, i = g & 1048575;
  const void* s = seg == 0 ? s0 : seg == 1 ? s1 : seg == 2 ? s2 : s3;
  bf16* d = seg == 0 ? d0 : seg == 1 ? d1 : seg == 2 ? d2 : d3;
  d[i] = fl ? f2b(((const float*)s)[i]) : ((const bf16*)s)[i];
}

// ---------------- small-matrix transpose+convert [K,N] -> [N,K] bf16 ----
__global__ void transpose_cvt(const void* __restrict__ src, bf16* __restrict__ dst,
                              int K, int Nd, const int* __restrict__ flag) {
  int fl = *flag;
  int idx = blockIdx.x * 256 + threadIdx.x;
  if (idx >= K * Nd) return;
  int k = idx / Nd, n = idx - k * Nd;
  float v = ldin(src, idx, fl);
  dst[(size_t)n * K + k] = f2b(v);
}

// ---------------- token-shift mix ----------------
__global__ __launch_bounds__(256)
void mix_kernel(const void* __restrict__ x,
    const void* __restrict__ mr, const void* __restrict__ mw, const void* __restrict__ mk,
    const void* __restrict__ mv, const void* __restrict__ ma, const void* __restrict__ mg,
    const int* __restrict__ flag,
    bf16* __restrict__ oxr, bf16* __restrict__ oxw, bf16* __restrict__ oxk,
    bf16* __restrict__ oxv, bf16* __restrict__ oxa, bf16* __restrict__ oxg)
{
  int fl = *flag;
  size_t idx = (size_t)blockIdx.x * 256 + threadIdx.x;   // over 4096*1024
  int c = (int)(idx & 1023);
  int t = (int)((idx >> 10) & 1023);
  float xc = ldin(x, idx, fl);
  float px = (t == 0) ? 0.f : ldin(x, idx - 1024, fl);
  float dx = px - xc;
  oxr[idx] = f2b(xc + ldin(mr, c, fl) * dx);
  oxw[idx] = f2b(xc + ldin(mw, c, fl) * dx);
  oxk[idx] = f2b(xc + ldin(mk, c, fl) * dx);
  oxv[idx] = f2b(xc + ldin(mv, c, fl) * dx);
  oxa[idx] = f2b(xc + ldin(ma, c, fl) * dx);
  oxg[idx] = f2b(xc + ldin(mg, c, fl) * dx);
}

// ---------------- MFMA GEMM: C[M,N] = A[M,K] * B[N,K]^T ----------------
// EPI: 0 f32 | 1 bf16 | 2 bf16 tanh | 3 bf16 sigmoid | 4 PKb slot bf16
//      5 WDEC->PKw f32 | 6 ASIG->PKb slot3 | 7 VBLEND->PKb slot2 | 8 out dual
template<int EPI>
__global__ __launch_bounds__(256)
void gemm_bt(const bf16* __restrict__ A, const bf16* __restrict__ Bw,
             int K, int Brows, int NS, int ldOut,
             float* __restrict__ outF, bf16* __restrict__ outB,
             bf16* __restrict__ pkb, float* __restrict__ pkw, int slot,
             const void* __restrict__ bias, const void* __restrict__ vfirst,
             const int* __restrict__ flag)
{
  __shared__ short As[128 * 32];
  __shared__ short Bs[128 * 32];
  int fl = *flag;
  const int tid = threadIdx.x;
  const int wid = tid >> 6, lane = tid & 63;
  const int m0 = blockIdx.x * 128, n0 = blockIdx.y * 128;
  const int wr = (wid >> 1) * 64, wc = (wid & 1) * 64;

  f32x4 acc[4][4] = {};

  const int lrow = lane >> 2;
  const int lcol = (lane & 3) * 8;
  int arow0 = m0 + (wid * 2 + 0) * 16 + lrow;
  int arow1 = m0 + (wid * 2 + 1) * 16 + lrow;
  int brow0 = n0 + (wid * 2 + 0) * 16 + lrow; if (brow0 >= Brows) brow0 = Brows - 1;
  int brow1 = n0 + (wid * 2 + 1) * 16 + lrow; if (brow1 >= Brows) brow1 = Brows - 1;

  const short* Ag = (const short*)A;
  const short* Bg = (const short*)Bw;

  for (int kk = 0; kk < K; kk += 32) {
    __syncthreads();
    g2lds16(Ag + (size_t)arow0 * K + kk + lcol, As + (wid * 2 + 0) * 512);
    g2lds16(Ag + (size_t)arow1 * K + kk + lcol, As + (wid * 2 + 1) * 512);
    g2lds16(Bg + (size_t)brow0 * K + kk + lcol, Bs + (wid * 2 + 0) * 512);
    g2lds16(Bg + (size_t)brow1 * K + kk + lcol, Bs + (wid * 2 + 1) * 512);
    __syncthreads();
    bf16x8 af[4], bfr[4];
#pragma unroll
    for (int mi = 0; mi < 4; mi++)
      af[mi] = *(const bf16x8*)(As + (wr + mi * 16 + (lane & 15)) * 32 + (lane >> 4) * 8);
#pragma unroll
    for (int ni = 0; ni < 4; ni++)
      bfr[ni] = *(const bf16x8*)(Bs + (wc + ni * 16 + (lane & 15)) * 32 + (lane >> 4) * 8);
#pragma unroll
    for (int mi = 0; mi < 4; mi++)
#pragma unroll
      for (int ni = 0; ni < 4; ni++)
        acc[mi][ni] = __builtin_amdgcn_mfma_f32_16x16x32_bf16(af[mi], bfr[ni], acc[mi][ni], 0, 0, 0);
  }

  // C/D: col = lane&15, row = (lane>>4)*4 + reg
  const int cl0 = lane & 15, r0 = (lane >> 4) * 4;
#pragma unroll
  for (int mi = 0; mi < 4; mi++) {
#pragma unroll
    for (int ni = 0; ni < 4; ni++) {
      int col = n0 + wc + ni * 16 + cl0;
      if (col >= NS) continue;
#pragma unroll
      for (int rr = 0; rr < 4; rr++) {
        int row = m0 + wr + mi * 16 + r0 + rr;
        float f = acc[mi][ni][rr];
        if constexpr (EPI == 0) {
          outF[(size_t)row * ldOut + col] = f;
        } else if constexpr (EPI == 1) {
          outB[(size_t)row * ldOut + col] = f2b(f);
        } else if constexpr (EPI == 2) {
          outB[(size_t)row * ldOut + col] = f2b(tanhf(f));
        } else if constexpr (EPI == 3) {
          outB[(size_t)row * ldOut + col] = f2b(sigm(f));
        } else if constexpr (EPI == 4) {
          pkb[(size_t)row * 5120 + (col >> 6) * 320 + slot * 64 + (col & 63)] = f2b(f);
        } else if constexpr (EPI == 5) {
          float z = -(ldin(bias, col, fl) + f);
          float sp = fmaxf(z, 0.f) + __logf(1.f + __expf(-fabsf(z)));
          pkw[(size_t)row * 1024 + col] = __expf(-__expf(-sp - 0.5f));
        } else if constexpr (EPI == 6) {
          pkb[(size_t)row * 5120 + (col >> 6) * 320 + 192 + (col & 63)] =
              f2b(sigm(ldin(bias, col, fl) + f));
        } else if constexpr (EPI == 7) {
          float sg = sigm(ldin(bias, col, fl) + f);
          size_t pa = (size_t)row * 5120 + (col >> 6) * 320 + 128 + (col & 63);
          float vr = b2f(pkb[pa]);
          float vf = ldin(vfirst, (size_t)row * 1024 + col, fl);
          pkb[pa] = f2b(vr + (vf - vr) * sg);
        } else if constexpr (EPI == 8) {
          if (fl) outF[(size_t)row * ldOut + col] = f;
          else    outB[(size_t)row * ldOut + col] = f2b(f);
        }
      }
    }
  }
}

// ---------------- per-(t,h) finalize: kkn, b, k_final ----------------
// PKb slots: 0=r 1=kraw->kfinal 2=v 3=asig->kkn 4=b
__global__ __launch_bounds__(256)
void post_kernel(bf16* __restrict__ PKb, const void* __restrict__ kkw,
                 const void* __restrict__ kaw, const int* __restrict__ flag) {
  int fl = *flag;
  int slot = blockIdx.x * 4 + (threadIdx.x >> 6);   // tg*16 + h
  int tg = slot >> 4, h = slot & 15;
  int n = threadIdx.x & 63, c = h * 64 + n;
  size_t pb = (size_t)tg * 5120 + (size_t)h * 320;
  float kraw = b2f(PKb[pb + 64 + n]);
  float asig = b2f(PKb[pb + 192 + n]);
  float kk = kraw * ldin(kkw, c, fl);
  float ss = kk * kk;
  ss += __shfl_xor(ss, 1);  ss += __shfl_xor(ss, 2);  ss += __shfl_xor(ss, 4);
  ss += __shfl_xor(ss, 8);  ss += __shfl_xor(ss, 16); ss += __shfl_xor(ss, 32);
  float kkn = kk / fmaxf(sqrtf(ss), 1e-12f);
  PKb[pb + 192 + n] = f2b(kkn);
  PKb[pb + 256 + n] = f2b(-kkn * asig);
  PKb[pb + 64 + n]  = f2b(kraw * (1.f + (asig - 1.f) * ldin(kaw, c, fl)));
}

// ---------------- sequential recurrence ----------------
// 256 blocks: bh = blk&63 (4 siblings same XCD), q = blk>>6 -> rows [q*16,+16)
// buf layout (f32): 0=r 64=k 128=v 192=a 256=b 320=wdec
__global__ __launch_bounds__(256)
void recur_kernel(const bf16* __restrict__ PKb, const float* __restrict__ PKw,
                  float* __restrict__ Y) {
  __shared__ __align__(16) float buf[2][384];
  int bh = blockIdx.x & 63, q = blockIdx.x >> 6;
  int b = bh >> 4, h = bh & 15;
  int tid = threadIdx.x, rl = tid >> 4, jq = tid & 15, j0 = jq * 4, i = q * 16 + rl;
  float S0 = 0.f, S1 = 0.f, S2 = 0.f, S3 = 0.f;
  const unsigned* pb = (const unsigned*)(PKb + (size_t)(b * 16384 + h) * 320);
  const float* pw = PKw + (size_t)b * 1024 * 1024 + h * 64;
  if (tid < 160) {
    unsigned u = pb[tid];
    buf[0][tid * 2]     = bfbits2f((unsigned short)(u & 0xffffu));
    buf[0][tid * 2 + 1] = bfbits2f((unsigned short)(u >> 16));
  } else if (tid >= 192) {
    buf[0][320 + (tid - 192)] = pw[tid - 192];
  }
  __syncthreads();
  for (int t = 0; t < 1024; ++t) {
    int cur = t & 1;
    unsigned pu = 0; float pwv = 0.f;
    const bool pf = (t + 1) < 1024;
    if (pf) {
      if (tid < 160) pu = pb[(size_t)(t + 1) * 2560 + tid];
      else if (tid >= 192) pwv = pw[(size_t)(t + 1) * 1024 + (tid - 192)];
    }
    const float* v = buf[cur];
    float4 rv = *(const float4*)(v + j0);
    float4 kv = *(const float4*)(v + 64 + j0);
    float4 av = *(const float4*)(v + 192 + j0);
    float4 bv = *(const float4*)(v + 256 + j0);
    float4 wv = *(const float4*)(v + 320 + j0);
    float vi = v[128 + i];
    float sa = S0 * av.x + S1 * av.y + S2 * av.z + S3 * av.w;
    sa += __shfl_xor(sa, 1); sa += __shfl_xor(sa, 2);
    sa += __shfl_xor(sa, 4); sa += __shfl_xor(sa, 8);
    S0 = S0 * wv.x + sa * bv.x + vi * kv.x;
    S1 = S1 * wv.y + sa * bv.y + vi * kv.y;
    S2 = S2 * wv.z + sa * bv.z + vi * kv.z;
    S3 = S3 * wv.w + sa * bv.w + vi * kv.w;
    float y = S0 * rv.x + S1 * rv.y + S2 * rv.z + S3 * rv.w;
    y += __shfl_xor(y, 1); y += __shfl_xor(y, 2);
    y += __shfl_xor(y, 4); y += __shfl_xor(y, 8);
    if (jq == 0) Y[((size_t)b * 1024 + t) * 1024 + h * 64 + i] = y;
    if (pf) {
      int nxt = cur ^ 1;
      if (tid < 160) {
        buf[nxt][tid * 2]     = bfbits2f((unsigned short)(pu & 0xffffu));
        buf[nxt][tid * 2 + 1] = bfbits2f((unsigned short)(pu >> 16));
      } else if (tid >= 192) {
        buf[nxt][320 + (tid - 192)] = pwv;
      }
    }
    __syncthreads();
  }
}

// ---------------- GroupNorm + residual + g gate ----------------
__global__ __launch_bounds__(256)
void gn_kernel(const float* __restrict__ Y, const bf16* __restrict__ PKb,
               const float* __restrict__ G,
               const void* __restrict__ gw, const void* __restrict__ gb,
               const void* __restrict__ rk, const int* __restrict__ flag,
               bf16* __restrict__ Z)
{
  int fl = *flag;
  int slot = blockIdx.x * 4 + (threadIdx.x >> 6);
  int tg = slot >> 4, h = slot & 15;
  int n = threadIdx.x & 63, c = h * 64 + n;
  size_t pb = (size_t)tg * 5120 + (size_t)h * 320;
  float y = Y[(size_t)tg * 1024 + c];
  float rr = b2f(PKb[pb + n]), kf = b2f(PKb[pb + 64 + n]), vv = b2f(PKb[pb + 128 + n]);
  float s1 = y, s2 = y * y, s3 = rr * kf * ldin(rk, c, fl);
#pragma unroll
  for (int m = 1; m < 64; m <<= 1) {
    s1 += __shfl_xor(s1, m);
    s2 += __shfl_xor(s2, m);
    s3 += __shfl_xor(s3, m);
  }
  float mu = s1 * 0.015625f;
  float var = s2 * 0.015625f - mu * mu;
  float xn = (y - mu) * rsqrtf(var + 0.00064f);
  float yn = xn * ldin(gw, c, fl) + ldin(gb, c, fl);
  yn += s3 * vv;
  Z[(size_t)tg * 1024 + c] = f2b(yn * G[(size_t)tg * 1024 + c]);
}

extern "C" void kernel_launch(void* const* d_in, const int* in_sizes, int n_in,
                              void* d_out, int out_size, void* d_ws, size_t ws_size,
                              hipStream_t stream)
{
  const void* x      = d_in[0];
  const void* vfirst = d_in[1];
  const void* m_r = d_in[2];  const void* m_w = d_in[3];
  const void* m_k = d_in[4];  const void* m_v = d_in[5];
  const void* m_a = d_in[6];  const void* m_g = d_in[7];
  const void* w0  = d_in[8];  const void* w1  = d_in[9];  const void* w2  = d_in[10];
  const void* a0  = d_in[11]; const void* a1  = d_in[12]; const void* a2  = d_in[13];
  const void* v0p = d_in[14]; const void* v1  = d_in[15]; const void* v2  = d_in[16];
  const void* g1  = d_in[17]; const void* g2  = d_in[18];
  const void* k_k = d_in[19]; const void* k_a = d_in[20]; const void* r_k = d_in[21];
  const void* W_r = d_in[22]; const void* W_k = d_in[23];
  const void* W_v = d_in[24]; const void* W_o = d_in[25];
  const void* gnw = d_in[26]; const void* gnb = d_in[27];
  (void)in_sizes; (void)n_in; (void)out_size; (void)ws_size;

  char* ws = (char*)d_ws;
  size_t off = 0;
  auto alloc = [&](size_t bytes) -> void* {
    void* p = ws + off; off += (bytes + 255) & ~(size_t)255; return p;
  };
  const size_t BTC2 = (size_t)4096 * 1024 * 2;
  int*  flag = (int*)alloc(256);
  bf16* cWr = (bf16*)alloc((size_t)1048576 * 2);
  bf16* cWk = (bf16*)alloc((size_t)1048576 * 2);
  bf16* cWv = (bf16*)alloc((size_t)1048576 * 2);
  bf16* cWo = (bf16*)alloc((size_t)1048576 * 2);
  bf16* w1t = (bf16*)alloc((size_t)65536 * 2);
  bf16* w2t = (bf16*)alloc((size_t)65536 * 2);
  bf16* a1t = (bf16*)alloc((size_t)65536 * 2);
  bf16* a2t = (bf16*)alloc((size_t)65536 * 2);
  bf16* v1t = (bf16*)alloc((size_t)32768 * 2);
  bf16* v2t = (bf16*)alloc((size_t)32768 * 2);
  bf16* g1t = (bf16*)alloc((size_t)163840 * 2);
  bf16* g2t = (bf16*)alloc((size_t)163840 * 2);
  bf16* xr = (bf16*)alloc(BTC2);
  bf16* xw = (bf16*)alloc(BTC2);
  bf16* xk = (bf16*)alloc(BTC2);
  bf16* xv = (bf16*)alloc(BTC2);
  bf16* xa = (bf16*)alloc(BTC2);
  bf16* xg = (bf16*)alloc(BTC2);
  bf16* PKb = (bf16*)alloc((size_t)4096 * 5120 * 2);   // [BT][H][5][64]
  float* PKw = (float*)alloc((size_t)4096 * 1024 * 4); // [BT][C] wdec
  bf16* hw  = (bf16*)alloc((size_t)4096 * 64 * 2);
  bf16* ha  = (bf16*)alloc((size_t)4096 * 64 * 2);
  bf16* hv  = (bf16*)alloc((size_t)4096 * 32 * 2);
  bf16* hg  = (bf16*)alloc((size_t)4096 * 160 * 2);
  // dead-buffer reuse (lifetimes verified by launch order):
  float* G = (float*)xr;   // 16 MiB over xr+xw; written after both consumed
  float* Y = (float*)xk;   // 16 MiB over xk+xv
  bf16*  Z = xa;           // 8 MiB

  detect_kernel<<<1, 256, 0, stream>>>((const unsigned*)x, flag);
  cvtw_kernel<<<16384, 256, 0, stream>>>(W_r, W_k, W_v, W_o, cWr, cWk, cWv, cWo, flag);

  auto tgrid = [](int n) { return dim3((n + 255) / 256); };
  transpose_cvt<<<tgrid(1024 * 64), 256, 0, stream>>>(w1, w1t, 1024, 64, flag);
  transpose_cvt<<<tgrid(64 * 1024), 256, 0, stream>>>(w2, w2t, 64, 1024, flag);
  transpose_cvt<<<tgrid(1024 * 64), 256, 0, stream>>>(a1, a1t, 1024, 64, flag);
  transpose_cvt<<<tgrid(64 * 1024), 256, 0, stream>>>(a2, a2t, 64, 1024, flag);
  transpose_cvt<<<tgrid(1024 * 32), 256, 0, stream>>>(v1, v1t, 1024, 32, flag);
  transpose_cvt<<<tgrid(32 * 1024), 256, 0, stream>>>(v2, v2t, 32, 1024, flag);
  transpose_cvt<<<tgrid(1024 * 160), 256, 0, stream>>>(g1, g1t, 1024, 160, flag);
  transpose_cvt<<<tgrid(160 * 1024), 256, 0, stream>>>(g2, g2t, 160, 1024, flag);

  mix_kernel<<<16384, 256, 0, stream>>>(x, m_r, m_w, m_k, m_v, m_a, m_g, flag,
                                        xr, xw, xk, xv, xa, xg);

  dim3 gBig(32, 8), gN64(32, 1), gN160(32, 2);
  // big projections -> PKb slots (r=0, kraw=1, vraw=2)
  gemm_bt<4><<<gBig, 256, 0, stream>>>(xr, cWr, 1024, 1024, 1024, 0, nullptr, nullptr, PKb, nullptr, 0, nullptr, nullptr, flag);
  gemm_bt<4><<<gBig, 256, 0, stream>>>(xk, cWk, 1024, 1024, 1024, 0, nullptr, nullptr, PKb, nullptr, 1, nullptr, nullptr, flag);
  gemm_bt<4><<<gBig, 256, 0, stream>>>(xv, cWv, 1024, 1024, 1024, 0, nullptr, nullptr, PKb, nullptr, 2, nullptr, nullptr, flag);
  // low-rank stage 1
  gemm_bt<2><<<gN64, 256, 0, stream>>>(xw, w1t, 1024, 64, 64, 64, nullptr, hw, nullptr, nullptr, 0, nullptr, nullptr, flag);
  gemm_bt<1><<<gN64, 256, 0, stream>>>(xa, a1t, 1024, 64, 64, 64, nullptr, ha, nullptr, nullptr, 0, nullptr, nullptr, flag);
  gemm_bt<1><<<gN64, 256, 0, stream>>>(xv, v1t, 1024, 32, 32, 32, nullptr, hv, nullptr, nullptr, 0, nullptr, nullptr, flag);
  gemm_bt<3><<<gN160, 256, 0, stream>>>(xg, g1t, 1024, 160, 160, 160, nullptr, hg, nullptr, nullptr, 0, nullptr, nullptr, flag);
  // low-rank stage 2 (fused epilogues)
  gemm_bt<5><<<gBig, 256, 0, stream>>>(hw, w2t, 64, 1024, 1024, 0, nullptr, nullptr, nullptr, PKw, 0, w0, nullptr, flag);
  gemm_bt<6><<<gBig, 256, 0, stream>>>(ha, a2t, 64, 1024, 1024, 0, nullptr, nullptr, PKb, nullptr, 0, a0, nullptr, flag);
  gemm_bt<7><<<gBig, 256, 0, stream>>>(hv, v2t, 32, 1024, 1024, 0, nullptr, nullptr, PKb, nullptr, 0, v0p, vfirst, flag);
  gemm_bt<0><<<gBig, 256, 0, stream>>>(hg, g2t, 160, 1024, 1024, 1024, G, nullptr, nullptr, nullptr, 0, nullptr, nullptr, flag);

  post_kernel<<<16384, 256, 0, stream>>>(PKb, k_k, k_a, flag);
  recur_kernel<<<256, 256, 0, stream>>>(PKb, PKw, Y);
  gn_kernel<<<16384, 256, 0, stream>>>(Y, PKb, G, gnw, gnb, r_k, flag, Z);

  gemm_bt<8><<<gBig, 256, 0, stream>>>(Z, cWo, 1024, 1024, 1024, 1024,
                                       (float*)d_out, (bf16*)d_out, nullptr, nullptr, 0, nullptr, nullptr, flag);
}

// Round 3
// 895.079 us; speedup vs baseline: 1.1469x; 1.1469x over previous
//
#include <hip/hip_runtime.h>
#include <hip/hip_bf16.h>
#include <math.h>

// RWKV-7 Tmix forward, B=4 T=1024 C=1024 H=16 N=64.
// R3: wave-autonomous recurrence (no LDS, no barriers, 8-deep register
// prefetch, DPP row_ror reductions). Input dtype (f32 vs bf16) runtime-detected.

using bf16 = __hip_bfloat16;
typedef __attribute__((ext_vector_type(8))) short bf16x8;
typedef __attribute__((ext_vector_type(4))) float f32x4;

#define DEVINL __device__ __forceinline__

DEVINL float b2f(bf16 v) { return __bfloat162float(v); }
DEVINL bf16 f2b(float f) { return __float2bfloat16(f); }
DEVINL float sigm(float x) { return 1.f / (1.f + __expf(-x)); }
DEVINL float bfbits2f(unsigned short s) { return __uint_as_float(((unsigned)s) << 16); }
DEVINL float ldin(const void* p, size_t i, int fl) {
  return fl ? ((const float*)p)[i] : b2f(((const bf16*)p)[i]);
}

DEVINL void g2lds16(const void* g, void* l) {
  __builtin_amdgcn_global_load_lds(
      (__attribute__((address_space(1))) void*)(g),
      (__attribute__((address_space(3))) void*)(l), 16, 0, 0);
}

// DPP rotate-add full 16-lane-row sum (VALU pipe, no DS ops)
template<int CTRL>
DEVINL float dpp_add(float x) {
  int t = __builtin_amdgcn_update_dpp(0, __float_as_int(x), CTRL, 0xf, 0xf, true);
  return x + __int_as_float(t);
}
DEVINL float rowsum16(float x) {
  x = dpp_add<0x121>(x);  // row_ror:1
  x = dpp_add<0x122>(x);  // row_ror:2
  x = dpp_add<0x124>(x);  // row_ror:4
  x = dpp_add<0x128>(x);  // row_ror:8
  return x;
}

// ---------------- dtype probe: flag=1 -> inputs are f32 ----------------
__global__ void detect_kernel(const unsigned* __restrict__ x, int* __restrict__ flag) {
  __shared__ int cnt[4];
  int tid = threadIdx.x;
  unsigned w = x[tid];
  float v = fabsf(bfbits2f((unsigned short)(w & 0xffffu)));
  bool plaus = (v >= 1e-4f && v <= 16.f);
  unsigned long long m = __ballot(plaus);
  if ((tid & 63) == 0) cnt[tid >> 6] = __popcll(m);
  __syncthreads();
  if (tid == 0) *flag = (cnt[0] + cnt[1] + cnt[2] + cnt[3] < 128) ? 1 : 0;
}

// ---------------- big-weight convert (4 x 1M elements) ----------------
__global__ __launch_bounds__(256)
void cvtw_kernel(const void* s0, const void* s1, const void* s2, const void* s3,
                 bf16* d0, bf16* d1, bf16* d2, bf16* d3, const int* __restrict__ flag) {
  int fl = *flag;
  int g = blockIdx.x * 256 + threadIdx.x;
  int seg = g >> 20, i = g & 1048575;
  const void* s = seg == 0 ? s0 : seg == 1 ? s1 : seg == 2 ? s2 : s3;
  bf16* d = seg == 0 ? d0 : seg == 1 ? d1 : seg == 2 ? d2 : d3;
  d[i] = fl ? f2b(((const float*)s)[i]) : ((const bf16*)s)[i];
}

// ------------ all 8 small transposes [K,N]->[N,K] in one launch ------------
__global__ __launch_bounds__(256)
void transpose_all(const void* s0, const void* s1, const void* s2, const void* s3,
                   const void* s4, const void* s5, const void* s6, const void* s7,
                   bf16* d0, bf16* d1, bf16* d2, bf16* d3,
                   bf16* d4, bf16* d5, bf16* d6, bf16* d7,
                   const int* __restrict__ flag) {
  int fl = *flag;
  int seg = blockIdx.y;
  const int Ks[8] = {1024, 64, 1024, 64, 1024, 32, 1024, 160};
  const int Nd[8] = {64, 1024, 64, 1024, 32, 1024, 160, 1024};
  const void* srcs[8] = {s0, s1, s2, s3, s4, s5, s6, s7};
  bf16* dsts[8] = {d0, d1, d2, d3, d4, d5, d6, d7};
  int K = Ks[seg], N = Nd[seg];
  int idx = blockIdx.x * 256 + threadIdx.x;
  if (idx >= K * N) return;
  int k = idx / N, n = idx - k * N;
  dsts[seg][(size_t)n * K + k] = f2b(ldin(srcs[seg], idx, fl));
}

// ---------------- token-shift mix ----------------
__global__ __launch_bounds__(256)
void mix_kernel(const void* __restrict__ x,
    const void* __restrict__ mr, const void* __restrict__ mw, const void* __restrict__ mk,
    const void* __restrict__ mv, const void* __restrict__ ma, const void* __restrict__ mg,
    const int* __restrict__ flag,
    bf16* __restrict__ oxr, bf16* __restrict__ oxw, bf16* __restrict__ oxk,
    bf16* __restrict__ oxv, bf16* __restrict__ oxa, bf16* __restrict__ oxg)
{
  int fl = *flag;
  size_t idx = (size_t)blockIdx.x * 256 + threadIdx.x;
  int c = (int)(idx & 1023);
  int t = (int)((idx >> 10) & 1023);
  float xc = ldin(x, idx, fl);
  float px = (t == 0) ? 0.f : ldin(x, idx - 1024, fl);
  float dx = px - xc;
  oxr[idx] = f2b(xc + ldin(mr, c, fl) * dx);
  oxw[idx] = f2b(xc + ldin(mw, c, fl) * dx);
  oxk[idx] = f2b(xc + ldin(mk, c, fl) * dx);
  oxv[idx] = f2b(xc + ldin(mv, c, fl) * dx);
  oxa[idx] = f2b(xc + ldin(ma, c, fl) * dx);
  oxg[idx] = f2b(xc + ldin(mg, c, fl) * dx);
}

// ---------------- MFMA GEMM: C[M,N] = A[M,K] * B[N,K]^T ----------------
// EPI: 0 f32 | 1 bf16 | 2 bf16 tanh | 3 bf16 sigmoid | 4 PKb slot bf16
//      5 WDEC->PKw f32 | 6 ASIG->PKb slot3 | 7 VBLEND->PKb slot2 | 8 out dual
template<int EPI>
__global__ __launch_bounds__(256)
void gemm_bt(const bf16* __restrict__ A, const bf16* __restrict__ Bw,
             int K, int Brows, int NS, int ldOut,
             float* __restrict__ outF, bf16* __restrict__ outB,
             bf16* __restrict__ pkb, float* __restrict__ pkw, int slot,
             const void* __restrict__ bias, const void* __restrict__ vfirst,
             const int* __restrict__ flag)
{
  __shared__ short As[128 * 32];
  __shared__ short Bs[128 * 32];
  int fl = *flag;
  const int tid = threadIdx.x;
  const int wid = tid >> 6, lane = tid & 63;
  const int m0 = blockIdx.x * 128, n0 = blockIdx.y * 128;
  const int wr = (wid >> 1) * 64, wc = (wid & 1) * 64;

  f32x4 acc[4][4] = {};

  const int lrow = lane >> 2;
  const int lcol = (lane & 3) * 8;
  int arow0 = m0 + (wid * 2 + 0) * 16 + lrow;
  int arow1 = m0 + (wid * 2 + 1) * 16 + lrow;
  int brow0 = n0 + (wid * 2 + 0) * 16 + lrow; if (brow0 >= Brows) brow0 = Brows - 1;
  int brow1 = n0 + (wid * 2 + 1) * 16 + lrow; if (brow1 >= Brows) brow1 = Brows - 1;

  const short* Ag = (const short*)A;
  const short* Bg = (const short*)Bw;

  for (int kk = 0; kk < K; kk += 32) {
    __syncthreads();
    g2lds16(Ag + (size_t)arow0 * K + kk + lcol, As + (wid * 2 + 0) * 512);
    g2lds16(Ag + (size_t)arow1 * K + kk + lcol, As + (wid * 2 + 1) * 512);
    g2lds16(Bg + (size_t)brow0 * K + kk + lcol, Bs + (wid * 2 + 0) * 512);
    g2lds16(Bg + (size_t)brow1 * K + kk + lcol, Bs + (wid * 2 + 1) * 512);
    __syncthreads();
    bf16x8 af[4], bfr[4];
#pragma unroll
    for (int mi = 0; mi < 4; mi++)
      af[mi] = *(const bf16x8*)(As + (wr + mi * 16 + (lane & 15)) * 32 + (lane >> 4) * 8);
#pragma unroll
    for (int ni = 0; ni < 4; ni++)
      bfr[ni] = *(const bf16x8*)(Bs + (wc + ni * 16 + (lane & 15)) * 32 + (lane >> 4) * 8);
#pragma unroll
    for (int mi = 0; mi < 4; mi++)
#pragma unroll
      for (int ni = 0; ni < 4; ni++)
        acc[mi][ni] = __builtin_amdgcn_mfma_f32_16x16x32_bf16(af[mi], bfr[ni], acc[mi][ni], 0, 0, 0);
  }

  const int cl0 = lane & 15, r0 = (lane >> 4) * 4;
#pragma unroll
  for (int mi = 0; mi < 4; mi++) {
#pragma unroll
    for (int ni = 0; ni < 4; ni++) {
      int col = n0 + wc + ni * 16 + cl0;
      if (col >= NS) continue;
#pragma unroll
      for (int rr = 0; rr < 4; rr++) {
        int row = m0 + wr + mi * 16 + r0 + rr;
        float f = acc[mi][ni][rr];
        if constexpr (EPI == 0) {
          outF[(size_t)row * ldOut + col] = f;
        } else if constexpr (EPI == 1) {
          outB[(size_t)row * ldOut + col] = f2b(f);
        } else if constexpr (EPI == 2) {
          outB[(size_t)row * ldOut + col] = f2b(tanhf(f));
        } else if constexpr (EPI == 3) {
          outB[(size_t)row * ldOut + col] = f2b(sigm(f));
        } else if constexpr (EPI == 4) {
          pkb[(size_t)row * 5120 + (col >> 6) * 320 + slot * 64 + (col & 63)] = f2b(f);
        } else if constexpr (EPI == 5) {
          float z = -(ldin(bias, col, fl) + f);
          float sp = fmaxf(z, 0.f) + __logf(1.f + __expf(-fabsf(z)));
          pkw[(size_t)row * 1024 + col] = __expf(-__expf(-sp - 0.5f));
        } else if constexpr (EPI == 6) {
          pkb[(size_t)row * 5120 + (col >> 6) * 320 + 192 + (col & 63)] =
              f2b(sigm(ldin(bias, col, fl) + f));
        } else if constexpr (EPI == 7) {
          float sg = sigm(ldin(bias, col, fl) + f);
          size_t pa = (size_t)row * 5120 + (col >> 6) * 320 + 128 + (col & 63);
          float vr = b2f(pkb[pa]);
          float vf = ldin(vfirst, (size_t)row * 1024 + col, fl);
          pkb[pa] = f2b(vr + (vf - vr) * sg);
        } else if constexpr (EPI == 8) {
          if (fl) outF[(size_t)row * ldOut + col] = f;
          else    outB[(size_t)row * ldOut + col] = f2b(f);
        }
      }
    }
  }
}

// ---------------- per-(t,h) finalize: kkn, b, k_final ----------------
// PKb slots: 0=r 1=kraw->kfinal 2=v 3=asig->kkn 4=b
__global__ __launch_bounds__(256)
void post_kernel(bf16* __restrict__ PKb, const void* __restrict__ kkw,
                 const void* __restrict__ kaw, const int* __restrict__ flag) {
  int fl = *flag;
  int slot = blockIdx.x * 4 + (threadIdx.x >> 6);
  int tg = slot >> 4, h = slot & 15;
  int n = threadIdx.x & 63, c = h * 64 + n;
  size_t pb = (size_t)tg * 5120 + (size_t)h * 320;
  float kraw = b2f(PKb[pb + 64 + n]);
  float asig = b2f(PKb[pb + 192 + n]);
  float kk = kraw * ldin(kkw, c, fl);
  float ss = kk * kk;
  ss += __shfl_xor(ss, 1);  ss += __shfl_xor(ss, 2);  ss += __shfl_xor(ss, 4);
  ss += __shfl_xor(ss, 8);  ss += __shfl_xor(ss, 16); ss += __shfl_xor(ss, 32);
  float kkn = kk / fmaxf(sqrtf(ss), 1e-12f);
  PKb[pb + 192 + n] = f2b(kkn);
  PKb[pb + 256 + n] = f2b(-kkn * asig);
  PKb[pb + 64 + n]  = f2b(kraw * (1.f + (asig - 1.f) * ldin(kaw, c, fl)));
}

// ---------------- sequential recurrence: wave-autonomous ----------------
// 1024 blocks x 64 thr. blk = sib*64 + bh (sib 0..15 same-XCD for fixed bh).
// Wave owns rows [sib*4, sib*4+4); lane: rl=lane>>4 (row), jg=lane&15 (4 j's).
// No LDS, no barriers. RD-deep register prefetch; DPP rotate-add reductions.
// NOTE: prefetch overreads <=8 steps past PKb/PKw stream end for b=3 —
// lands in subsequent ws allocations (PKw / hw), values never used.
#define RD 8
__global__ __launch_bounds__(64)
void recur_kernel(const bf16* __restrict__ PKb, const float* __restrict__ PKw,
                  float* __restrict__ Y) {
  int blk = blockIdx.x;
  int bh = blk & 63, sib = blk >> 6;
  int b = bh >> 4, h = bh & 15;
  int lane = threadIdx.x;
  int jg = lane & 15, j0 = jg * 4;
  int rl = lane >> 4;
  int i = sib * 4 + rl;

  const unsigned short* pb =
      (const unsigned short*)(PKb) + ((size_t)b * 1024 * 16 + h) * 320;
  const float* pw = PKw + (size_t)b * 1024 * 1024 + h * 64;
  float* yout = Y + (size_t)b * 1024 * 1024 + h * 64 + i;

  uint2 Lr[RD], Lk[RD], La[RD], Lb[RD];
  float4 Lw[RD];
  unsigned short Lv[RD];

#pragma unroll
  for (int d = 0; d < RD; ++d) {
    const unsigned short* s = pb + (size_t)d * 5120;
    Lr[d] = *(const uint2*)(s + j0);
    Lk[d] = *(const uint2*)(s + 64 + j0);
    La[d] = *(const uint2*)(s + 192 + j0);
    Lb[d] = *(const uint2*)(s + 256 + j0);
    Lv[d] = s[128 + i];
    Lw[d] = *(const float4*)(pw + (size_t)d * 1024 + j0);
  }

  float S0 = 0.f, S1 = 0.f, S2 = 0.f, S3 = 0.f;

  for (int t0 = 0; t0 < 1024; t0 += RD) {
#pragma unroll
    for (int d = 0; d < RD; ++d) {
      int t = t0 + d;
      uint2 ur = Lr[d], uk = Lk[d], ua = La[d], ub = Lb[d];
      float4 wv = Lw[d];
      float vi = bfbits2f(Lv[d]);
      // prefetch step t+RD into slot d (overread past end is benign)
      {
        const unsigned short* s = pb + (size_t)(t + RD) * 5120;
        Lr[d] = *(const uint2*)(s + j0);
        Lk[d] = *(const uint2*)(s + 64 + j0);
        La[d] = *(const uint2*)(s + 192 + j0);
        Lb[d] = *(const uint2*)(s + 256 + j0);
        Lv[d] = s[128 + i];
        Lw[d] = *(const float4*)(pw + (size_t)(t + RD) * 1024 + j0);
      }
      float ax = bfbits2f((unsigned short)(ua.x & 0xffffu));
      float ay = bfbits2f((unsigned short)(ua.x >> 16));
      float az = bfbits2f((unsigned short)(ua.y & 0xffffu));
      float aw = bfbits2f((unsigned short)(ua.y >> 16));
      float kx = bfbits2f((unsigned short)(uk.x & 0xffffu));
      float ky = bfbits2f((unsigned short)(uk.x >> 16));
      float kz = bfbits2f((unsigned short)(uk.y & 0xffffu));
      float kw = bfbits2f((unsigned short)(uk.y >> 16));
      float bx = bfbits2f((unsigned short)(ub.x & 0xffffu));
      float by = bfbits2f((unsigned short)(ub.x >> 16));
      float bz = bfbits2f((unsigned short)(ub.y & 0xffffu));
      float bw = bfbits2f((unsigned short)(ub.y >> 16));
      float rx = bfbits2f((unsigned short)(ur.x & 0xffffu));
      float ry = bfbits2f((unsigned short)(ur.x >> 16));
      float rz = bfbits2f((unsigned short)(ur.y & 0xffffu));
      float rw = bfbits2f((unsigned short)(ur.y >> 16));

      float sa = (S0 * ax + S1 * ay) + (S2 * az + S3 * aw);
      sa = rowsum16(sa);
      S0 = S0 * wv.x + (sa * bx + vi * kx);
      S1 = S1 * wv.y + (sa * by + vi * ky);
      S2 = S2 * wv.z + (sa * bz + vi * kz);
      S3 = S3 * wv.w + (sa * bw + vi * kw);
      float y = (S0 * rx + S1 * ry) + (S2 * rz + S3 * rw);
      y = rowsum16(y);
      if (jg == 0) yout[(size_t)t * 1024] = y;
    }
  }
}

// ---------------- GroupNorm + residual + g gate ----------------
__global__ __launch_bounds__(256)
void gn_kernel(const float* __restrict__ Y, const bf16* __restrict__ PKb,
               const float* __restrict__ G,
               const void* __restrict__ gw, const void* __restrict__ gb,
               const void* __restrict__ rk, const int* __restrict__ flag,
               bf16* __restrict__ Z)
{
  int fl = *flag;
  int slot = blockIdx.x * 4 + (threadIdx.x >> 6);
  int tg = slot >> 4, h = slot & 15;
  int n = threadIdx.x & 63, c = h * 64 + n;
  size_t pb = (size_t)tg * 5120 + (size_t)h * 320;
  float y = Y[(size_t)tg * 1024 + c];
  float rr = b2f(PKb[pb + n]), kf = b2f(PKb[pb + 64 + n]), vv = b2f(PKb[pb + 128 + n]);
  float s1 = y, s2 = y * y, s3 = rr * kf * ldin(rk, c, fl);
#pragma unroll
  for (int m = 1; m < 64; m <<= 1) {
    s1 += __shfl_xor(s1, m);
    s2 += __shfl_xor(s2, m);
    s3 += __shfl_xor(s3, m);
  }
  float mu = s1 * 0.015625f;
  float var = s2 * 0.015625f - mu * mu;
  float xn = (y - mu) * rsqrtf(var + 0.00064f);
  float yn = xn * ldin(gw, c, fl) + ldin(gb, c, fl);
  yn += s3 * vv;
  Z[(size_t)tg * 1024 + c] = f2b(yn * G[(size_t)tg * 1024 + c]);
}

extern "C" void kernel_launch(void* const* d_in, const int* in_sizes, int n_in,
                              void* d_out, int out_size, void* d_ws, size_t ws_size,
                              hipStream_t stream)
{
  const void* x      = d_in[0];
  const void* vfirst = d_in[1];
  const void* m_r = d_in[2];  const void* m_w = d_in[3];
  const void* m_k = d_in[4];  const void* m_v = d_in[5];
  const void* m_a = d_in[6];  const void* m_g = d_in[7];
  const void* w0  = d_in[8];  const void* w1  = d_in[9];  const void* w2  = d_in[10];
  const void* a0  = d_in[11]; const void* a1  = d_in[12]; const void* a2  = d_in[13];
  const void* v0p = d_in[14]; const void* v1  = d_in[15]; const void* v2  = d_in[16];
  const void* g1  = d_in[17]; const void* g2  = d_in[18];
  const void* k_k = d_in[19]; const void* k_a = d_in[20]; const void* r_k = d_in[21];
  const void* W_r = d_in[22]; const void* W_k = d_in[23];
  const void* W_v = d_in[24]; const void* W_o = d_in[25];
  const void* gnw = d_in[26]; const void* gnb = d_in[27];
  (void)in_sizes; (void)n_in; (void)out_size; (void)ws_size;

  char* ws = (char*)d_ws;
  size_t off = 0;
  auto alloc = [&](size_t bytes) -> void* {
    void* p = ws + off; off += (bytes + 255) & ~(size_t)255; return p;
  };
  const size_t BTC2 = (size_t)4096 * 1024 * 2;
  int*  flag = (int*)alloc(256);
  bf16* cWr = (bf16*)alloc((size_t)1048576 * 2);
  bf16* cWk = (bf16*)alloc((size_t)1048576 * 2);
  bf16* cWv = (bf16*)alloc((size_t)1048576 * 2);
  bf16* cWo = (bf16*)alloc((size_t)1048576 * 2);
  bf16* w1t = (bf16*)alloc((size_t)65536 * 2);
  bf16* w2t = (bf16*)alloc((size_t)65536 * 2);
  bf16* a1t = (bf16*)alloc((size_t)65536 * 2);
  bf16* a2t = (bf16*)alloc((size_t)65536 * 2);
  bf16* v1t = (bf16*)alloc((size_t)32768 * 2);
  bf16* v2t = (bf16*)alloc((size_t)32768 * 2);
  bf16* g1t = (bf16*)alloc((size_t)163840 * 2);
  bf16* g2t = (bf16*)alloc((size_t)163840 * 2);
  bf16* xr = (bf16*)alloc(BTC2);
  bf16* xw = (bf16*)alloc(BTC2);
  bf16* xk = (bf16*)alloc(BTC2);
  bf16* xv = (bf16*)alloc(BTC2);
  bf16* xa = (bf16*)alloc(BTC2);
  bf16* xg = (bf16*)alloc(BTC2);
  bf16* PKb = (bf16*)alloc((size_t)4096 * 5120 * 2);   // [BT][H][5][64]
  float* PKw = (float*)alloc((size_t)4096 * 1024 * 4); // [BT][C] wdec
  bf16* hw  = (bf16*)alloc((size_t)4096 * 64 * 2);
  bf16* ha  = (bf16*)alloc((size_t)4096 * 64 * 2);
  bf16* hv  = (bf16*)alloc((size_t)4096 * 32 * 2);
  bf16* hg  = (bf16*)alloc((size_t)4096 * 160 * 2);
  // dead-buffer reuse (lifetimes verified by launch order):
  float* G = (float*)xr;   // over xr+xw
  float* Y = (float*)xk;   // over xk+xv
  bf16*  Z = xa;

  detect_kernel<<<1, 256, 0, stream>>>((const unsigned*)x, flag);
  cvtw_kernel<<<16384, 256, 0, stream>>>(W_r, W_k, W_v, W_o, cWr, cWk, cWv, cWo, flag);
  transpose_all<<<dim3(640, 8), 256, 0, stream>>>(w1, w2, a1, a2, v1, v2, g1, g2,
                                                  w1t, w2t, a1t, a2t, v1t, v2t, g1t, g2t, flag);
  mix_kernel<<<16384, 256, 0, stream>>>(x, m_r, m_w, m_k, m_v, m_a, m_g, flag,
                                        xr, xw, xk, xv, xa, xg);

  dim3 gBig(32, 8), gN64(32, 1), gN160(32, 2);
  gemm_bt<4><<<gBig, 256, 0, stream>>>(xr, cWr, 1024, 1024, 1024, 0, nullptr, nullptr, PKb, nullptr, 0, nullptr, nullptr, flag);
  gemm_bt<4><<<gBig, 256, 0, stream>>>(xk, cWk, 1024, 1024, 1024, 0, nullptr, nullptr, PKb, nullptr, 1, nullptr, nullptr, flag);
  gemm_bt<4><<<gBig, 256, 0, stream>>>(xv, cWv, 1024, 1024, 1024, 0, nullptr, nullptr, PKb, nullptr, 2, nullptr, nullptr, flag);
  gemm_bt<2><<<gN64, 256, 0, stream>>>(xw, w1t, 1024, 64, 64, 64, nullptr, hw, nullptr, nullptr, 0, nullptr, nullptr, flag);
  gemm_bt<1><<<gN64, 256, 0, stream>>>(xa, a1t, 1024, 64, 64, 64, nullptr, ha, nullptr, nullptr, 0, nullptr, nullptr, flag);
  gemm_bt<1><<<gN64, 256, 0, stream>>>(xv, v1t, 1024, 32, 32, 32, nullptr, hv, nullptr, nullptr, 0, nullptr, nullptr, flag);
  gemm_bt<3><<<gN160, 256, 0, stream>>>(xg, g1t, 1024, 160, 160, 160, nullptr, hg, nullptr, nullptr, 0, nullptr, nullptr, flag);
  gemm_bt<5><<<gBig, 256, 0, stream>>>(hw, w2t, 64, 1024, 1024, 0, nullptr, nullptr, nullptr, PKw, 0, w0, nullptr, flag);
  gemm_bt<6><<<gBig, 256, 0, stream>>>(ha, a2t, 64, 1024, 1024, 0, nullptr, nullptr, PKb, nullptr, 0, a0, nullptr, flag);
  gemm_bt<7><<<gBig, 256, 0, stream>>>(hv, v2t, 32, 1024, 1024, 0, nullptr, nullptr, PKb, nullptr, 0, v0p, vfirst, flag);
  gemm_bt<0><<<gBig, 256, 0, stream>>>(hg, g2t, 160, 1024, 1024, 1024, G, nullptr, nullptr, nullptr, 0, nullptr, nullptr, flag);

  post_kernel<<<16384, 256, 0, stream>>>(PKb, k_k, k_a, flag);
  recur_kernel<<<1024, 64, 0, stream>>>(PKb, PKw, Y);
  gn_kernel<<<16384, 256, 0, stream>>>(Y, PKb, G, gnw, gnb, r_k, flag, Z);

  gemm_bt<8><<<gBig, 256, 0, stream>>>(Z, cWo, 1024, 1024, 1024, 1024,
                                       (float*)d_out, (bf16*)d_out, nullptr, nullptr, 0, nullptr, nullptr, flag);
}

// Round 4
// 608.629 us; speedup vs baseline: 1.6867x; 1.4706x over previous
//
#include <hip/hip_runtime.h>
#include <hip/hip_bf16.h>
#include <math.h>

// RWKV-7 Tmix forward, B=4 T=1024 C=1024 H=16 N=64.
// R4: recurrence at 2 waves/SIMD (2048 waves, 2 rows/wave, DPP+swizzle
// reductions, 8-deep register prefetch); launches fused 21 -> 9.
// Input dtype (f32 vs bf16) runtime-detected.

using bf16 = __hip_bfloat16;
typedef __attribute__((ext_vector_type(8))) short bf16x8;
typedef __attribute__((ext_vector_type(4))) float f32x4;

#define DEVINL __device__ __forceinline__

DEVINL float b2f(bf16 v) { return __bfloat162float(v); }
DEVINL bf16 f2b(float f) { return __float2bfloat16(f); }
DEVINL float sigm(float x) { return 1.f / (1.f + __expf(-x)); }
DEVINL float bfbits2f(unsigned short s) { return __uint_as_float(((unsigned)s) << 16); }
DEVINL float ldin(const void* p, size_t i, int fl) {
  return fl ? ((const float*)p)[i] : b2f(((const bf16*)p)[i]);
}

DEVINL void g2lds16(const void* g, void* l) {
  __builtin_amdgcn_global_load_lds(
      (__attribute__((address_space(1))) void*)(g),
      (__attribute__((address_space(3))) void*)(l), 16, 0, 0);
}

// DPP rotate-add 16-lane-row sum + ds_swizzle xor-16 for 32-lane groups
template<int CTRL>
DEVINL float dpp_add(float x) {
  int t = __builtin_amdgcn_update_dpp(0, __float_as_int(x), CTRL, 0xf, 0xf, true);
  return x + __int_as_float(t);
}
DEVINL float rowsum32(float x) {
  x = dpp_add<0x121>(x);  // row_ror:1
  x = dpp_add<0x122>(x);  // row_ror:2
  x = dpp_add<0x124>(x);  // row_ror:4
  x = dpp_add<0x128>(x);  // row_ror:8
  int t = __builtin_amdgcn_ds_swizzle(__float_as_int(x), 0x401F);  // xor 16
  return x + __int_as_float(t);
}

// ---------------- dtype probe: flag=1 -> inputs are f32 ----------------
__global__ void detect_kernel(const unsigned* __restrict__ x, int* __restrict__ flag) {
  __shared__ int cnt[4];
  int tid = threadIdx.x;
  unsigned w = x[tid];
  float v = fabsf(bfbits2f((unsigned short)(w & 0xffffu)));
  bool plaus = (v >= 1e-4f && v <= 16.f);
  unsigned long long m = __ballot(plaus);
  if ((tid & 63) == 0) cnt[tid >> 6] = __popcll(m);
  __syncthreads();
  if (tid == 0) *flag = (cnt[0] + cnt[1] + cnt[2] + cnt[3] < 128) ? 1 : 0;
}

// ---------------- prep: mix + big-weight cvt + 8 small transposes ----------------
__global__ __launch_bounds__(256)
void prep_kernel(const void* __restrict__ x,
    const void* mr, const void* mw, const void* mk,
    const void* mv, const void* ma, const void* mg,
    const void* W_r, const void* W_k, const void* W_v, const void* W_o,
    bf16* cWr, bf16* cWk, bf16* cWv, bf16* cWo,
    const void* w1, const void* w2, const void* a1, const void* a2,
    const void* v1, const void* v2, const void* g1, const void* g2,
    bf16* w1t, bf16* w2t, bf16* a1t, bf16* a2t,
    bf16* v1t, bf16* v2t, bf16* g1t, bf16* g2t,
    const int* __restrict__ flag,
    bf16* oxr, bf16* oxw, bf16* oxk, bf16* oxv, bf16* oxa, bf16* oxg)
{
  int fl = *flag;
  int bx = blockIdx.x;
  if (bx < 16384) {                       // token-shift mix over 4M
    size_t idx = (size_t)bx * 256 + threadIdx.x;
    int c = (int)(idx & 1023);
    int t = (int)((idx >> 10) & 1023);
    float xc = ldin(x, idx, fl);
    float px = (t == 0) ? 0.f : ldin(x, idx - 1024, fl);
    float dx = px - xc;
    oxr[idx] = f2b(xc + ldin(mr, c, fl) * dx);
    oxw[idx] = f2b(xc + ldin(mw, c, fl) * dx);
    oxk[idx] = f2b(xc + ldin(mk, c, fl) * dx);
    oxv[idx] = f2b(xc + ldin(mv, c, fl) * dx);
    oxa[idx] = f2b(xc + ldin(ma, c, fl) * dx);
    oxg[idx] = f2b(xc + ldin(mg, c, fl) * dx);
  } else if (bx < 32768) {                // big-weight convert, 4 x 1M
    int g = (bx - 16384) * 256 + threadIdx.x;
    int seg = g >> 20, i = g & 1048575;
    const void* s = seg == 0 ? W_r : seg == 1 ? W_k : seg == 2 ? W_v : W_o;
    bf16* d = seg == 0 ? cWr : seg == 1 ? cWk : seg == 2 ? cWv : cWo;
    d[i] = fl ? f2b(((const float*)s)[i]) : ((const bf16*)s)[i];
  } else {                                // 8 small transposes [K,N]->[N,K]
    int idx = (bx - 32768) * 256 + threadIdx.x;
    if (idx >= 655360) return;
    const int ends[8] = {65536, 131072, 196608, 262144, 294912, 327680, 491520, 655360};
    const int Ks[8] = {1024, 64, 1024, 64, 1024, 32, 1024, 160};
    const int Nd[8] = {64, 1024, 64, 1024, 32, 1024, 160, 1024};
    const void* srcs[8] = {w1, w2, a1, a2, v1, v2, g1, g2};
    bf16* dsts[8] = {w1t, w2t, a1t, a2t, v1t, v2t, g1t, g2t};
    int seg = 0, start = 0;
#pragma unroll
    for (int s2 = 0; s2 < 7; s2++)
      if (idx >= ends[s2]) { seg = s2 + 1; start = ends[s2]; }
    int local = idx - start;
    int K = Ks[seg], N = Nd[seg];
    int k = local / N, n = local - k * N;
    dsts[seg][(size_t)n * K + k] = f2b(ldin(srcs[seg], local, fl));
  }
}

// ---------------- shared MFMA GEMM core: C[M,N] = A[M,K] * B[N,K]^T ----------------
// 128x128 tile, BK=32, 256 thr (4 waves 2x2, each 64x64 = 4x4 mfma 16x16x32)
template<typename Epi>
DEVINL void gemm_core(const bf16* __restrict__ A, const bf16* __restrict__ Bt,
                      int K, int Brows, int m0, int n0, Epi&& epi)
{
  __shared__ short As[128 * 32];
  __shared__ short Bs[128 * 32];
  const int tid = threadIdx.x;
  const int wid = tid >> 6, lane = tid & 63;
  const int wr = (wid >> 1) * 64, wc = (wid & 1) * 64;

  f32x4 acc[4][4] = {};

  const int lrow = lane >> 2;
  const int lcol = (lane & 3) * 8;
  int arow0 = m0 + (wid * 2 + 0) * 16 + lrow;
  int arow1 = m0 + (wid * 2 + 1) * 16 + lrow;
  int brow0 = n0 + (wid * 2 + 0) * 16 + lrow; if (brow0 >= Brows) brow0 = Brows - 1;
  int brow1 = n0 + (wid * 2 + 1) * 16 + lrow; if (brow1 >= Brows) brow1 = Brows - 1;

  const short* Ag = (const short*)A;
  const short* Bg = (const short*)Bt;

  for (int kk = 0; kk < K; kk += 32) {
    __syncthreads();
    g2lds16(Ag + (size_t)arow0 * K + kk + lcol, As + (wid * 2 + 0) * 512);
    g2lds16(Ag + (size_t)arow1 * K + kk + lcol, As + (wid * 2 + 1) * 512);
    g2lds16(Bg + (size_t)brow0 * K + kk + lcol, Bs + (wid * 2 + 0) * 512);
    g2lds16(Bg + (size_t)brow1 * K + kk + lcol, Bs + (wid * 2 + 1) * 512);
    __syncthreads();
    bf16x8 af[4], bfr[4];
#pragma unroll
    for (int mi = 0; mi < 4; mi++)
      af[mi] = *(const bf16x8*)(As + (wr + mi * 16 + (lane & 15)) * 32 + (lane >> 4) * 8);
#pragma unroll
    for (int ni = 0; ni < 4; ni++)
      bfr[ni] = *(const bf16x8*)(Bs + (wc + ni * 16 + (lane & 15)) * 32 + (lane >> 4) * 8);
#pragma unroll
    for (int mi = 0; mi < 4; mi++)
#pragma unroll
      for (int ni = 0; ni < 4; ni++)
        acc[mi][ni] = __builtin_amdgcn_mfma_f32_16x16x32_bf16(af[mi], bfr[ni], acc[mi][ni], 0, 0, 0);
  }

  const int cl0 = lane & 15, r0 = (lane >> 4) * 4;
#pragma unroll
  for (int mi = 0; mi < 4; mi++)
#pragma unroll
    for (int ni = 0; ni < 4; ni++) {
      int col = n0 + wc + ni * 16 + cl0;
#pragma unroll
      for (int rr = 0; rr < 4; rr++)
        epi(m0 + wr + mi * 16 + r0 + rr, col, acc[mi][ni][rr]);
    }
}

// ---------------- stage1: xw@w1 tanh | xa@a1 | xv@v1 | xg@g1 sigm ----------------
__global__ __launch_bounds__(256)
void stage1_kernel(const bf16* xw, const bf16* xa, const bf16* xv, const bf16* xg,
                   const bf16* w1t, const bf16* a1t, const bf16* v1t, const bf16* g1t,
                   bf16* hw, bf16* ha, bf16* hv, bf16* hg)
{
  int y = blockIdx.y;
  int seg = (y <= 2) ? y : 3;
  int n0 = (y == 4) ? 128 : 0;
  const bf16* A  = seg == 0 ? xw  : seg == 1 ? xa  : seg == 2 ? xv  : xg;
  const bf16* Bt = seg == 0 ? w1t : seg == 1 ? a1t : seg == 2 ? v1t : g1t;
  int NS         = seg == 0 ? 64  : seg == 1 ? 64  : seg == 2 ? 32  : 160;
  bf16* out      = seg == 0 ? hw  : seg == 1 ? ha  : seg == 2 ? hv  : hg;
  gemm_core(A, Bt, 1024, NS, blockIdx.x * 128, n0, [&](int row, int col, float f) {
    if (col >= NS) return;
    if (seg == 0) f = tanhf(f);
    else if (seg == 3) f = sigm(f);
    out[(size_t)row * NS + col] = f2b(f);
  });
}

// ---------------- big r/k/v projections -> PKb slots 0/1/2 ----------------
// PKb slots: 0=r 1=kraw->kfinal 2=v 3=asig->kkn 4=b
__global__ __launch_bounds__(256)
void bigrkv_kernel(const bf16* xr, const bf16* xk, const bf16* xv,
                   const bf16* cWr, const bf16* cWk, const bf16* cWv,
                   bf16* __restrict__ PKb)
{
  int z = blockIdx.z;
  const bf16* A  = z == 0 ? xr  : z == 1 ? xk  : xv;
  const bf16* Bt = z == 0 ? cWr : z == 1 ? cWk : cWv;
  gemm_core(A, Bt, 1024, 1024, blockIdx.x * 128, blockIdx.y * 128,
            [&](int row, int col, float f) {
    PKb[(size_t)row * 5120 + (col >> 6) * 320 + z * 64 + (col & 63)] = f2b(f);
  });
}

// ---------------- stage2: wdec->PKw | asig->slot3 | vblend->slot2 | G ----------------
__global__ __launch_bounds__(256)
void stage2_kernel(const bf16* hw, const bf16* ha, const bf16* hv, const bf16* hg,
                   const bf16* w2t, const bf16* a2t, const bf16* v2t, const bf16* g2t,
                   bf16* __restrict__ PKb, float* __restrict__ PKw, float* __restrict__ G,
                   const void* w0, const void* a0, const void* v0p, const void* vfirst,
                   const int* __restrict__ flag)
{
  int fl = *flag;
  int z = blockIdx.z;
  const bf16* A  = z == 0 ? hw  : z == 1 ? ha  : z == 2 ? hv  : hg;
  const bf16* Bt = z == 0 ? w2t : z == 1 ? a2t : z == 2 ? v2t : g2t;
  int K          = z == 0 ? 64  : z == 1 ? 64  : z == 2 ? 32  : 160;
  gemm_core(A, Bt, K, 1024, blockIdx.x * 128, blockIdx.y * 128,
            [&](int row, int col, float f) {
    if (z == 0) {
      float zz = -(ldin(w0, col, fl) + f);
      float sp = fmaxf(zz, 0.f) + __logf(1.f + __expf(-fabsf(zz)));
      PKw[(size_t)row * 1024 + col] = __expf(-__expf(-sp - 0.5f));
    } else if (z == 1) {
      PKb[(size_t)row * 5120 + (col >> 6) * 320 + 192 + (col & 63)] =
          f2b(sigm(ldin(a0, col, fl) + f));
    } else if (z == 2) {
      float sg = sigm(ldin(v0p, col, fl) + f);
      size_t pa = (size_t)row * 5120 + (col >> 6) * 320 + 128 + (col & 63);
      float vr = b2f(PKb[pa]);
      float vf = ldin(vfirst, (size_t)row * 1024 + col, fl);
      PKb[pa] = f2b(vr + (vf - vr) * sg);
    } else {
      G[(size_t)row * 1024 + col] = f;
    }
  });
}

// ---------------- per-(t,h) finalize: kkn, b, k_final ----------------
__global__ __launch_bounds__(256)
void post_kernel(bf16* __restrict__ PKb, const void* __restrict__ kkw,
                 const void* __restrict__ kaw, const int* __restrict__ flag) {
  int fl = *flag;
  int slot = blockIdx.x * 4 + (threadIdx.x >> 6);
  int tg = slot >> 4, h = slot & 15;
  int n = threadIdx.x & 63, c = h * 64 + n;
  size_t pb = (size_t)tg * 5120 + (size_t)h * 320;
  float kraw = b2f(PKb[pb + 64 + n]);
  float asig = b2f(PKb[pb + 192 + n]);
  float kk = kraw * ldin(kkw, c, fl);
  float ss = kk * kk;
  ss += __shfl_xor(ss, 1);  ss += __shfl_xor(ss, 2);  ss += __shfl_xor(ss, 4);
  ss += __shfl_xor(ss, 8);  ss += __shfl_xor(ss, 16); ss += __shfl_xor(ss, 32);
  float kkn = kk / fmaxf(sqrtf(ss), 1e-12f);
  PKb[pb + 192 + n] = f2b(kkn);
  PKb[pb + 256 + n] = f2b(-kkn * asig);
  PKb[pb + 64 + n]  = f2b(kraw * (1.f + (asig - 1.f) * ldin(kaw, c, fl)));
}

// ---------------- sequential recurrence: 2 waves/SIMD ----------------
// 2048 blocks x 64 thr. blk = sib*64 + bh (32 sibs per bh, same XCD).
// Wave owns rows [sib*2, sib*2+2); lane: rl=lane>>5 (row), jl=lane&31 (2 j's).
// No LDS, no barriers. RD-deep register prefetch; DPP+swizzle reductions.
// Overreads <=8 steps past PKb/PKw stream end (lands in PKw / hw ws regions).
#define RD 8
__global__ __launch_bounds__(64)
void recur_kernel(const bf16* __restrict__ PKb, const float* __restrict__ PKw,
                  float* __restrict__ Y) {
  int blk = blockIdx.x;
  int bh = blk & 63, sib = blk >> 6;
  int b = bh >> 4, h = bh & 15;
  int lane = threadIdx.x;
  int jl = lane & 31, j0 = jl * 2;
  int rl = lane >> 5;
  int i = sib * 2 + rl;

  const unsigned short* pb =
      (const unsigned short*)(PKb) + ((size_t)b * 1024 * 16 + h) * 320;
  const float* pw = PKw + (size_t)b * 1024 * 1024 + h * 64;
  float* yout = Y + (size_t)b * 1024 * 1024 + h * 64 + i;

  unsigned Lr[RD], Lk[RD], La[RD], Lb[RD];
  float2 Lw[RD];
  unsigned short Lv[RD];

#pragma unroll
  for (int d = 0; d < RD; ++d) {
    const unsigned short* s = pb + (size_t)d * 5120;
    Lr[d] = *(const unsigned*)(s + j0);
    Lk[d] = *(const unsigned*)(s + 64 + j0);
    La[d] = *(const unsigned*)(s + 192 + j0);
    Lb[d] = *(const unsigned*)(s + 256 + j0);
    Lv[d] = s[128 + i];
    Lw[d] = *(const float2*)(pw + (size_t)d * 1024 + j0);
  }

  float S0 = 0.f, S1 = 0.f;

  for (int t0 = 0; t0 < 1024; t0 += RD) {
#pragma unroll
    for (int d = 0; d < RD; ++d) {
      int t = t0 + d;
      unsigned ur = Lr[d], uk = Lk[d], ua = La[d], ub = Lb[d];
      float2 wv = Lw[d];
      float vi = bfbits2f(Lv[d]);
      {  // prefetch step t+RD into slot d (overread past end is benign)
        const unsigned short* s = pb + (size_t)(t + RD) * 5120;
        Lr[d] = *(const unsigned*)(s + j0);
        Lk[d] = *(const unsigned*)(s + 64 + j0);
        La[d] = *(const unsigned*)(s + 192 + j0);
        Lb[d] = *(const unsigned*)(s + 256 + j0);
        Lv[d] = s[128 + i];
        Lw[d] = *(const float2*)(pw + (size_t)(t + RD) * 1024 + j0);
      }
      float ax = bfbits2f((unsigned short)(ua & 0xffffu));
      float ay = bfbits2f((unsigned short)(ua >> 16));
      float kx = bfbits2f((unsigned short)(uk & 0xffffu));
      float ky = bfbits2f((unsigned short)(uk >> 16));
      float bx = bfbits2f((unsigned short)(ub & 0xffffu));
      float by = bfbits2f((unsigned short)(ub >> 16));
      float rx = bfbits2f((unsigned short)(ur & 0xffffu));
      float ry = bfbits2f((unsigned short)(ur >> 16));

      float sa = S0 * ax + S1 * ay;
      sa = rowsum32(sa);
      S0 = S0 * wv.x + (sa * bx + vi * kx);
      S1 = S1 * wv.y + (sa * by + vi * ky);
      float y = S0 * rx + S1 * ry;
      y = rowsum32(y);
      if (jl == 0) yout[(size_t)t * 1024] = y;
    }
  }
}

// ---------------- GroupNorm + residual + g gate ----------------
__global__ __launch_bounds__(256)
void gn_kernel(const float* __restrict__ Y, const bf16* __restrict__ PKb,
               const float* __restrict__ G,
               const void* __restrict__ gw, const void* __restrict__ gb,
               const void* __restrict__ rk, const int* __restrict__ flag,
               bf16* __restrict__ Z)
{
  int fl = *flag;
  int slot = blockIdx.x * 4 + (threadIdx.x >> 6);
  int tg = slot >> 4, h = slot & 15;
  int n = threadIdx.x & 63, c = h * 64 + n;
  size_t pb = (size_t)tg * 5120 + (size_t)h * 320;
  float y = Y[(size_t)tg * 1024 + c];
  float rr = b2f(PKb[pb + n]), kf = b2f(PKb[pb + 64 + n]), vv = b2f(PKb[pb + 128 + n]);
  float s1 = y, s2 = y * y, s3 = rr * kf * ldin(rk, c, fl);
#pragma unroll
  for (int m = 1; m < 64; m <<= 1) {
    s1 += __shfl_xor(s1, m);
    s2 += __shfl_xor(s2, m);
    s3 += __shfl_xor(s3, m);
  }
  float mu = s1 * 0.015625f;
  float var = s2 * 0.015625f - mu * mu;
  float xn = (y - mu) * rsqrtf(var + 0.00064f);
  float yn = xn * ldin(gw, c, fl) + ldin(gb, c, fl);
  yn += s3 * vv;
  Z[(size_t)tg * 1024 + c] = f2b(yn * G[(size_t)tg * 1024 + c]);
}

// ---------------- final output GEMM ----------------
__global__ __launch_bounds__(256)
void outgemm_kernel(const bf16* Z, const bf16* cWo,
                    float* oF, bf16* oB, const int* __restrict__ flag)
{
  int fl = *flag;
  gemm_core(Z, cWo, 1024, 1024, blockIdx.x * 128, blockIdx.y * 128,
            [&](int row, int col, float f) {
    if (fl) oF[(size_t)row * 1024 + col] = f;
    else    oB[(size_t)row * 1024 + col] = f2b(f);
  });
}

extern "C" void kernel_launch(void* const* d_in, const int* in_sizes, int n_in,
                              void* d_out, int out_size, void* d_ws, size_t ws_size,
                              hipStream_t stream)
{
  const void* x      = d_in[0];
  const void* vfirst = d_in[1];
  const void* m_r = d_in[2];  const void* m_w = d_in[3];
  const void* m_k = d_in[4];  const void* m_v = d_in[5];
  const void* m_a = d_in[6];  const void* m_g = d_in[7];
  const void* w0  = d_in[8];  const void* w1  = d_in[9];  const void* w2  = d_in[10];
  const void* a0  = d_in[11]; const void* a1  = d_in[12]; const void* a2  = d_in[13];
  const void* v0p = d_in[14]; const void* v1  = d_in[15]; const void* v2  = d_in[16];
  const void* g1  = d_in[17]; const void* g2  = d_in[18];
  const void* k_k = d_in[19]; const void* k_a = d_in[20]; const void* r_k = d_in[21];
  const void* W_r = d_in[22]; const void* W_k = d_in[23];
  const void* W_v = d_in[24]; const void* W_o = d_in[25];
  const void* gnw = d_in[26]; const void* gnb = d_in[27];
  (void)in_sizes; (void)n_in; (void)out_size; (void)ws_size;

  char* ws = (char*)d_ws;
  size_t off = 0;
  auto alloc = [&](size_t bytes) -> void* {
    void* p = ws + off; off += (bytes + 255) & ~(size_t)255; return p;
  };
  const size_t BTC2 = (size_t)4096 * 1024 * 2;
  int*  flag = (int*)alloc(256);
  bf16* cWr = (bf16*)alloc((size_t)1048576 * 2);
  bf16* cWk = (bf16*)alloc((size_t)1048576 * 2);
  bf16* cWv = (bf16*)alloc((size_t)1048576 * 2);
  bf16* cWo = (bf16*)alloc((size_t)1048576 * 2);
  bf16* w1t = (bf16*)alloc((size_t)65536 * 2);
  bf16* w2t = (bf16*)alloc((size_t)65536 * 2);
  bf16* a1t = (bf16*)alloc((size_t)65536 * 2);
  bf16* a2t = (bf16*)alloc((size_t)65536 * 2);
  bf16* v1t = (bf16*)alloc((size_t)32768 * 2);
  bf16* v2t = (bf16*)alloc((size_t)32768 * 2);
  bf16* g1t = (bf16*)alloc((size_t)163840 * 2);
  bf16* g2t = (bf16*)alloc((size_t)163840 * 2);
  bf16* xr = (bf16*)alloc(BTC2);
  bf16* xw = (bf16*)alloc(BTC2);
  bf16* xk = (bf16*)alloc(BTC2);
  bf16* xv = (bf16*)alloc(BTC2);
  bf16* xa = (bf16*)alloc(BTC2);
  bf16* xg = (bf16*)alloc(BTC2);
  bf16* PKb = (bf16*)alloc((size_t)4096 * 5120 * 2);   // [BT][H][5][64]
  float* PKw = (float*)alloc((size_t)4096 * 1024 * 4); // [BT][C] wdec
  bf16* hw  = (bf16*)alloc((size_t)4096 * 64 * 2);
  bf16* ha  = (bf16*)alloc((size_t)4096 * 64 * 2);
  bf16* hv  = (bf16*)alloc((size_t)4096 * 32 * 2);
  bf16* hg  = (bf16*)alloc((size_t)4096 * 160 * 2);
  // dead-buffer reuse (lifetimes verified by launch order):
  float* G = (float*)xr;   // over xr+xw; written by stage2 (after bigrkv/stage1 consume)
  float* Y = (float*)xk;   // over xk+xv; written by recur (after bigrkv/stage1 consume)
  bf16*  Z = xa;           // written by gn (after stage1 consumes xa)

  detect_kernel<<<1, 256, 0, stream>>>((const unsigned*)x, flag);
  prep_kernel<<<35328, 256, 0, stream>>>(
      x, m_r, m_w, m_k, m_v, m_a, m_g,
      W_r, W_k, W_v, W_o, cWr, cWk, cWv, cWo,
      w1, w2, a1, a2, v1, v2, g1, g2,
      w1t, w2t, a1t, a2t, v1t, v2t, g1t, g2t,
      flag, xr, xw, xk, xv, xa, xg);

  stage1_kernel<<<dim3(32, 5), 256, 0, stream>>>(xw, xa, xv, xg,
                                                 w1t, a1t, v1t, g1t, hw, ha, hv, hg);
  bigrkv_kernel<<<dim3(32, 8, 3), 256, 0, stream>>>(xr, xk, xv, cWr, cWk, cWv, PKb);
  stage2_kernel<<<dim3(32, 8, 4), 256, 0, stream>>>(hw, ha, hv, hg,
                                                    w2t, a2t, v2t, g2t,
                                                    PKb, PKw, G, w0, a0, v0p, vfirst, flag);
  post_kernel<<<16384, 256, 0, stream>>>(PKb, k_k, k_a, flag);
  recur_kernel<<<2048, 64, 0, stream>>>(PKb, PKw, Y);
  gn_kernel<<<16384, 256, 0, stream>>>(Y, PKb, G, gnw, gnb, r_k, flag, Z);
  outgemm_kernel<<<dim3(32, 8), 256, 0, stream>>>(Z, cWo, (float*)d_out, (bf16*)d_out, flag);
}